// Round 4
// baseline (336.433 us; speedup 1.0000x reference)
//
#include <hip/hip_runtime.h>

typedef float v4f __attribute__((ext_vector_type(4)));

#define BDIM   256
#define KK     9
#define CELLS  81
#define BOARD  729
#define BPB    4               // one board per wave, 4 waves per block
#define CHUNK  (BPB * BOARD)   // 2916 floats per block
#define LDSW   736             // per-wave LDS region (4 pre-pad + 732), floats

// Barrier-free design: each wave owns one board. Board starts are 4B-aligned
// only (729 odd), so the interior [4*g_lo, 4*g_hi) uses aligned dwordx4 and
// the <=3 head/tail floats use scalar dwords. Same-wave LDS round-trip needs
// only lgkmcnt -> zero __syncthreads, zero vmcnt(0) barrier drains.
__global__ __launch_bounds__(BDIM) void sudoku_iter_kernel(
    const float* __restrict__ sudoku,
    const float* __restrict__ rmask,
    const float* __restrict__ rindex,
    const float* __restrict__ conv_w,
    const float* __restrict__ conv_b,
    float* __restrict__ out,
    int Btot)
{
    __shared__ float lds_s[BPB * LDSW];   // 11776 B

    const int tid  = threadIdx.x;
    const int wave = tid >> 6;
    const int lane = tid & 63;
    const int blk  = blockIdx.x;
    const size_t base = (size_t)blk * CHUNK;

    // per-wave board geometry (block-local flat float indices)
    const int fstart = wave * BOARD;            // 0,729,1458,2187
    const int g_lo   = (fstart + 3) >> 2;       // first aligned v4f
    const int g_hi   = (fstart + BOARD) >> 2;   // one past last aligned v4f
    const int h      = 4 * g_lo - fstart;       // head floats: 0,3,2,1
    const int t      = fstart + BOARD - 4 * g_hi; // tail floats: 1,2,3,0
    const int n4     = g_hi - g_lo;             // interior v4f count: 182/181

    // ---- issue ALL global loads up front (sudoku, then rmask) ----
    const v4f* gs4 = (const v4f*)(sudoku + base);
    const v4f* gr4 = (const v4f*)(rmask  + base);
    v4f s4[3], r4[3];
    bool act[3];
    #pragma unroll
    for (int i = 0; i < 3; ++i) {
        int k2 = lane + 64 * i;
        act[i] = (k2 < n4);
        if (act[i]) s4[i] = gs4[g_lo + k2];
    }
    const bool hasH = (lane < h);
    const bool hasT = (lane >= 8) && (lane < 8 + t);
    const int  eH   = lane;                       // head element 0..h-1
    const int  eT   = BOARD - t + (lane - 8);     // tail element
    float sh = 0.f, st = 0.f, rh = 0.f, rt = 0.f;
    if (hasH) sh = sudoku[base + fstart + eH];
    if (hasT) st = sudoku[base + fstart + eT];
    #pragma unroll
    for (int i = 0; i < 3; ++i) {
        if (act[i]) r4[i] = gr4[g_lo + lane + 64 * i];
    }
    if (hasH) rh = rmask[base + fstart + eH];
    if (hasT) rt = rmask[base + fstart + eT];
    float ri0 = (lane == 0) ? rindex[blk * BPB + wave] : 0.f;

    float wreg[KK];
    #pragma unroll
    for (int n = 0; n < KK; ++n) wreg[n] = conv_w[n];
    const float bias = conv_b[0];
    const float cmp  = fminf(fmaxf(bias, 0.f), 1.f);

    // ---- stage board into this wave's private LDS region ----
    // element e of the board lives at bs[e]; interior v4f k lands at bs[h+4k..]
    float* bs  = lds_s + wave * LDSW + (4 - h);
    v4f*   bs4 = (v4f*)(lds_s + wave * LDSW + 4);      // 16B aligned
    #pragma unroll
    for (int i = 0; i < 3; ++i) {
        if (act[i]) bs4[lane + 64 * i] = s4[i];
    }
    if (hasH) bs[eH] = sh;
    if (hasT) bs[eT] = st;
    // compiler inserts lgkmcnt waits; same-wave RAW -> no barrier needed

    // ---- selection: argmax-first cell, then argmax-first number ----
    float v0; int i0;
    {
        const int cell = lane;
        float cnt = bias;
        #pragma unroll
        for (int n = 0; n < KK; ++n) cnt += bs[n * CELLS + cell] * wreg[n];
        float nic = fmaxf(cnt - 1.f, 0.f);
        float m0  = fminf(fmaxf(1.f - nic, 0.f), 1.f) * (-(float)KK);
        v0 = m0 - nic; i0 = cell;
    }
    if (lane < CELLS - 64) {     // cells 64..80
        const int cell = lane + 64;
        float cnt = bias;
        #pragma unroll
        for (int n = 0; n < KK; ++n) cnt += bs[n * CELLS + cell] * wreg[n];
        float nic = fmaxf(cnt - 1.f, 0.f);
        float m0  = fminf(fmaxf(1.f - nic, 0.f), 1.f) * (-(float)KK);
        float v1 = m0 - nic;
        if (v1 > v0) { v0 = v1; i0 = cell; }   // strict > keeps smaller index
    }
    #pragma unroll
    for (int off = 32; off > 0; off >>= 1) {
        float ov = __shfl_xor(v0, off, 64);
        int   oi = __shfl_xor(i0, off, 64);
        if (ov > v0 || (ov == v0 && oi < i0)) { v0 = ov; i0 = oi; }
    }
    float m = 0.f, cms = 0.f; int es = 0, cellstar = 0;
    if (lane == 0) {
        cellstar = i0;
        m = bs[cellstar]; int nstar = 0;        // first-argmax over numbers
        #pragma unroll
        for (int n = 1; n < KK; ++n) {
            float v = bs[n * CELLS + cellstar];
            if (v > m) { m = v; nstar = n; }
        }
        es  = nstar * CELLS + cellstar;
        cms = fminf(fmaxf(m * wreg[nstar] + bias, 0.f), 1.f);
    }
    m        = __shfl(m, 0, 64);
    cms      = __shfl(cms, 0, 64);
    es       = __shfl(es, 0, 64);
    cellstar = __shfl(cellstar, 0, 64);
    const float ri = __shfl(ri0, 0, 64);

    // ---- epilogue (board-local; all meta in registers) ----
    v4f* os4 = (v4f*)(out + base);
    v4f* or4 = (v4f*)(out + (size_t)Btot * BOARD + base);
    const int ebase = h + 4 * lane;          // element of s4[0].x
    const int cbase = ebase % CELLS;
    const int iadd[3] = {0, 13, 26};         // (256*i) % 81

    #pragma unroll
    for (int i = 0; i < 3; ++i) {
        if (act[i]) {
            float so[4], ro[4];
            const float* sp = (const float*)&s4[i];
            const float* rp = (const float*)&r4[i];
            #pragma unroll
            for (int j = 0; j < 4; ++j) {
                int e = ebase + 256 * i + j;
                int cell = cbase + iadd[i] + j;
                if (cell >= CELLS) cell -= CELLS;
                float s  = sp[j];
                float rm = rp[j];
                float ov  = (e == es) ? m : 0.f;
                float cm  = (cell == cellstar) ? cms : cmp;
                float orm = s * cm * (1.f - ov);
                float rmo = fmaxf(rm, ri * orm);
                rmo = fmaxf(rmo, (ri - 1.f) * ov);
                so[j] = s * (1.f - orm);
                ro[j] = rmo;
            }
            v4f sv; sv.x = so[0]; sv.y = so[1]; sv.z = so[2]; sv.w = so[3];
            v4f rv; rv.x = ro[0]; rv.y = ro[1]; rv.z = ro[2]; rv.w = ro[3];
            __builtin_nontemporal_store(sv, &os4[g_lo + lane + 64 * i]);
            __builtin_nontemporal_store(rv, &or4[g_lo + lane + 64 * i]);
        }
    }
    // head/tail scalar elements
    if (hasH | hasT) {
        int   e  = hasH ? eH : eT;
        float s  = hasH ? sh : st;
        float rm = hasH ? rh : rt;
        int cell = (e >= 648) ? (e - 648) : e;   // head e<=2 -> cell=e; tail e>=726
        float ov  = (e == es) ? m : 0.f;
        float cm  = (cell == cellstar) ? cms : cmp;
        float orm = s * cm * (1.f - ov);
        float rmo = fmaxf(rm, ri * orm);
        rmo = fmaxf(rmo, (ri - 1.f) * ov);
        __builtin_nontemporal_store(s * (1.f - orm), out + base + fstart + e);
        __builtin_nontemporal_store(rmo, out + (size_t)Btot * BOARD + base + fstart + e);
    }

    // recursion_index + 1 (one float per board)
    if (lane == 0) {
        out[(size_t)Btot * BOARD * 2 + (size_t)blk * BPB + wave] = ri + 1.f;
    }
}

extern "C" void kernel_launch(void* const* d_in, const int* in_sizes, int n_in,
                              void* d_out, int out_size, void* d_ws, size_t ws_size,
                              hipStream_t stream) {
    const float* sudoku = (const float*)d_in[0];
    const float* rmask  = (const float*)d_in[1];
    const float* rindex = (const float*)d_in[2];
    const float* conv_w = (const float*)d_in[3];
    const float* conv_b = (const float*)d_in[4];
    float* out = (float*)d_out;

    const int Btot = in_sizes[2];            // 32768 boards
    const int nblocks = Btot / BPB;          // 8192 blocks, 1 board per wave

    sudoku_iter_kernel<<<nblocks, BDIM, 0, stream>>>(
        sudoku, rmask, rindex, conv_w, conv_b, out, Btot);
}

// Round 5
// 336.188 us; speedup vs baseline: 1.0007x; 1.0007x over previous
//
#include <hip/hip_runtime.h>

typedef float v4f __attribute__((ext_vector_type(4)));

#define BDIM   256
#define KK     9
#define CELLS  81
#define BOARD  729
#define BPB    4               // one board per wave, 4 waves per block
#define CHUNK  (BPB * BOARD)   // 2916 floats per block
#define LDSW   736             // per-wave region size in floats (4 pre-pad + 732)

// Barrier-free: each wave owns one board, staging BOTH sudoku and rmask
// through its private LDS region. The ds_writes force all 6 global dwordx4
// loads to issue up front (full MLP) — the compiler cannot sink them.
__global__ __launch_bounds__(BDIM) void sudoku_iter_kernel(
    const float* __restrict__ sudoku,
    const float* __restrict__ rmask,
    const float* __restrict__ rindex,
    const float* __restrict__ conv_w,
    const float* __restrict__ conv_b,
    float* __restrict__ out,
    int Btot)
{
    __shared__ float lds_s[BPB * 2 * LDSW];   // 23552 B

    const int tid  = threadIdx.x;
    const int wave = tid >> 6;
    const int lane = tid & 63;
    const int blk  = blockIdx.x;
    const size_t base = (size_t)blk * CHUNK;

    // per-wave board geometry (block-local flat float indices)
    const int fstart = wave * BOARD;              // 0,729,1458,2187
    const int g_lo   = (fstart + 3) >> 2;         // first aligned v4f
    const int g_hi   = (fstart + BOARD) >> 2;     // one past last aligned v4f
    const int h      = 4 * g_lo - fstart;         // head floats: 0,3,2,1
    const int t      = fstart + BOARD - 4 * g_hi; // tail floats: 1,2,3,0
    const int n4     = g_hi - g_lo;               // interior v4f count: 182/181

    // ---- issue ALL global loads up front (sudoku, then rmask) ----
    const v4f* gs4 = (const v4f*)(sudoku + base);
    const v4f* gr4 = (const v4f*)(rmask  + base);
    v4f s4[3], r4[3];
    bool act[3];
    #pragma unroll
    for (int i = 0; i < 3; ++i) {
        int k2 = lane + 64 * i;
        act[i] = (k2 < n4);
        if (act[i]) s4[i] = gs4[g_lo + k2];
    }
    const bool hasH = (lane < h);
    const bool hasT = (lane >= 8) && (lane < 8 + t);
    const int  eH   = lane;                       // head element 0..h-1
    const int  eT   = BOARD - t + (lane - 8);     // tail element
    float sh = 0.f, st = 0.f, rh = 0.f, rt = 0.f;
    if (hasH) sh = sudoku[base + fstart + eH];
    if (hasT) st = sudoku[base + fstart + eT];
    #pragma unroll
    for (int i = 0; i < 3; ++i) {
        if (act[i]) r4[i] = gr4[g_lo + lane + 64 * i];
    }
    if (hasH) rh = rmask[base + fstart + eH];
    if (hasT) rt = rmask[base + fstart + eT];

    float wreg[KK];
    #pragma unroll
    for (int n = 0; n < KK; ++n) wreg[n] = conv_w[n];
    const float bias = conv_b[0];
    const float cmp  = fminf(fmaxf(bias, 0.f), 1.f);
    const float ri   = rindex[blk * BPB + wave];   // uniform -> scalarized

    // ---- stage BOTH operands into this wave's private LDS regions ----
    float* sb  = lds_s + wave * 2 * LDSW + (4 - h);       // element e at sb[e]
    float* rb  = sb + LDSW;
    v4f*   sb4 = (v4f*)(lds_s + wave * 2 * LDSW + 4);     // 16B aligned
    v4f*   rb4 = (v4f*)(lds_s + wave * 2 * LDSW + LDSW + 4);
    #pragma unroll
    for (int i = 0; i < 3; ++i) {
        if (act[i]) sb4[lane + 64 * i] = s4[i];
    }
    if (hasH) sb[eH] = sh;
    if (hasT) sb[eT] = st;
    #pragma unroll
    for (int i = 0; i < 3; ++i) {
        if (act[i]) rb4[lane + 64 * i] = r4[i];
    }
    if (hasH) rb[eH] = rh;
    if (hasT) rb[eT] = rt;
    // same-wave LDS RAW -> lgkmcnt only, no __syncthreads anywhere

    // ---- selection: argmax-first cell, then argmax-first number ----
    float v0; int i0;
    {
        const int cell = lane;
        float cnt = bias;
        #pragma unroll
        for (int n = 0; n < KK; ++n) cnt += sb[n * CELLS + cell] * wreg[n];
        float nic = fmaxf(cnt - 1.f, 0.f);
        float m0  = fminf(fmaxf(1.f - nic, 0.f), 1.f) * (-(float)KK);
        v0 = m0 - nic; i0 = cell;
    }
    if (lane < CELLS - 64) {     // cells 64..80
        const int cell = lane + 64;
        float cnt = bias;
        #pragma unroll
        for (int n = 0; n < KK; ++n) cnt += sb[n * CELLS + cell] * wreg[n];
        float nic = fmaxf(cnt - 1.f, 0.f);
        float m0  = fminf(fmaxf(1.f - nic, 0.f), 1.f) * (-(float)KK);
        float v1 = m0 - nic;
        if (v1 > v0) { v0 = v1; i0 = cell; }   // strict > keeps smaller index
    }
    #pragma unroll
    for (int off = 32; off > 0; off >>= 1) {
        float ov = __shfl_xor(v0, off, 64);
        int   oi = __shfl_xor(i0, off, 64);
        if (ov > v0 || (ov == v0 && oi < i0)) { v0 = ov; i0 = oi; }
    }
    // after the butterfly ALL lanes hold the argmax cell -> no broadcasts:
    // every lane redundantly does the 9-way number argmax via same-address
    // LDS reads (bank broadcast, conflict-free).
    const int cellstar = i0;
    float m = sb[cellstar]; int nstar = 0;
    #pragma unroll
    for (int n = 1; n < KK; ++n) {
        float v = sb[n * CELLS + cellstar];
        if (v > m) { m = v; nstar = n; }
    }
    const int   es  = nstar * CELLS + cellstar;
    const float cms = fminf(fmaxf(m * wreg[nstar] + bias, 0.f), 1.f);

    // ---- epilogue: both operands from LDS (ds_read_b128), meta in registers ----
    v4f* os4 = (v4f*)(out + base);
    v4f* or4 = (v4f*)(out + (size_t)Btot * BOARD + base);
    const int ebase = h + 4 * lane;          // element of interior v4f lane,i=0
    const int cbase = ebase % CELLS;
    const int iadd[3] = {0, 13, 26};         // (256*i) % 81

    #pragma unroll
    for (int i = 0; i < 3; ++i) {
        if (act[i]) {
            v4f sv4 = sb4[lane + 64 * i];
            v4f rv4 = rb4[lane + 64 * i];
            float so[4], ro[4];
            const float* sp = (const float*)&sv4;
            const float* rp = (const float*)&rv4;
            #pragma unroll
            for (int j = 0; j < 4; ++j) {
                int e = ebase + 256 * i + j;
                int cell = cbase + iadd[i] + j;
                if (cell >= CELLS) cell -= CELLS;
                float s  = sp[j];
                float rm = rp[j];
                float ov  = (e == es) ? m : 0.f;
                float cm  = (cell == cellstar) ? cms : cmp;
                float orm = s * cm * (1.f - ov);
                float rmo = fmaxf(rm, ri * orm);
                rmo = fmaxf(rmo, (ri - 1.f) * ov);
                so[j] = s * (1.f - orm);
                ro[j] = rmo;
            }
            v4f sv; sv.x = so[0]; sv.y = so[1]; sv.z = so[2]; sv.w = so[3];
            v4f rv; rv.x = ro[0]; rv.y = ro[1]; rv.z = ro[2]; rv.w = ro[3];
            __builtin_nontemporal_store(sv, &os4[g_lo + lane + 64 * i]);
            __builtin_nontemporal_store(rv, &or4[g_lo + lane + 64 * i]);
        }
    }
    // head/tail scalar elements (from LDS)
    if (hasH | hasT) {
        int   e  = hasH ? eH : eT;
        float s  = sb[e];
        float rm = rb[e];
        int cell = (e >= 648) ? (e - 648) : e;   // head e<=2 -> cell=e; tail e>=726
        float ov  = (e == es) ? m : 0.f;
        float cm  = (cell == cellstar) ? cms : cmp;
        float orm = s * cm * (1.f - ov);
        float rmo = fmaxf(rm, ri * orm);
        rmo = fmaxf(rmo, (ri - 1.f) * ov);
        __builtin_nontemporal_store(s * (1.f - orm), out + base + fstart + e);
        __builtin_nontemporal_store(rmo, out + (size_t)Btot * BOARD + base + fstart + e);
    }

    // recursion_index + 1 (one float per board)
    if (lane == 0) {
        out[(size_t)Btot * BOARD * 2 + (size_t)blk * BPB + wave] = ri + 1.f;
    }
}

extern "C" void kernel_launch(void* const* d_in, const int* in_sizes, int n_in,
                              void* d_out, int out_size, void* d_ws, size_t ws_size,
                              hipStream_t stream) {
    const float* sudoku = (const float*)d_in[0];
    const float* rmask  = (const float*)d_in[1];
    const float* rindex = (const float*)d_in[2];
    const float* conv_w = (const float*)d_in[3];
    const float* conv_b = (const float*)d_in[4];
    float* out = (float*)d_out;

    const int Btot = in_sizes[2];            // 32768 boards
    const int nblocks = Btot / BPB;          // 8192 blocks, 1 board per wave

    sudoku_iter_kernel<<<nblocks, BDIM, 0, stream>>>(
        sudoku, rmask, rindex, conv_w, conv_b, out, Btot);
}

// Round 6
// 332.797 us; speedup vs baseline: 1.0109x; 1.0102x over previous
//
#include <hip/hip_runtime.h>

typedef float v4f __attribute__((ext_vector_type(4)));

#define KK      9
#define CELLS   81
#define BOARD   729
#define B1      8                      // boards per block (select): 8*729*4 B = 23328 B, 16B-aligned
#define SEL_V4  (B1 * BOARD / 4)       // 1458 v4f per select block
#define AP_V4   1024                   // v4f per apply block (256 threads x 4)

// ---------------- Kernel 1: per-board selection ----------------
// 8 boards/block, 32 threads per board. Stages sudoku via dwordx4 into LDS,
// computes (argmax-first cell, argmax-first number, m, cms, ri) and writes a
// 16B meta record per board into d_ws, plus the ri+1 output.
__global__ __launch_bounds__(256) void select_kernel(
    const float* __restrict__ sudoku,
    const float* __restrict__ rindex,
    const float* __restrict__ conv_w,
    const float* __restrict__ conv_b,
    v4f*   __restrict__ meta,          // [Btot] in d_ws
    float* __restrict__ out_ri,        // out + 2*Btot*BOARD
    int Btot)
{
    __shared__ float sb[B1 * BOARD];   // 23328 B

    const int tid = threadIdx.x;
    const int blk = blockIdx.x;
    const size_t base = (size_t)blk * (B1 * BOARD);

    // staging: 1458 v4f, fully coalesced, no head/tail (base is 16B-aligned)
    const v4f* g4 = (const v4f*)(sudoku + base);
    v4f* s4 = (v4f*)sb;
    #pragma unroll
    for (int k = 0; k < 6; ++k) {
        int idx = tid + k * 256;
        if (idx < SEL_V4) s4[idx] = g4[idx];
    }

    float wreg[KK];
    #pragma unroll
    for (int n = 0; n < KK; ++n) wreg[n] = conv_w[n];
    const float bias = conv_b[0];

    __syncthreads();

    const int g = tid >> 5;            // board within block (0..7)
    const int l = tid & 31;            // lane within 32-thread group
    const float* bs = sb + g * BOARD;
    const int board = blk * B1 + g;

    // cells l, l+32, l+64 in ascending order (strict > keeps first max)
    float v0; int i0;
    {
        const int cell = l;
        float cnt = bias;
        #pragma unroll
        for (int n = 0; n < KK; ++n) cnt += bs[n * CELLS + cell] * wreg[n];
        float nic = fmaxf(cnt - 1.f, 0.f);
        float m0  = fminf(fmaxf(1.f - nic, 0.f), 1.f) * (-(float)KK);
        v0 = m0 - nic; i0 = cell;
    }
    {
        const int cell = l + 32;
        float cnt = bias;
        #pragma unroll
        for (int n = 0; n < KK; ++n) cnt += bs[n * CELLS + cell] * wreg[n];
        float nic = fmaxf(cnt - 1.f, 0.f);
        float m0  = fminf(fmaxf(1.f - nic, 0.f), 1.f) * (-(float)KK);
        float v1 = m0 - nic;
        if (v1 > v0) { v0 = v1; i0 = cell; }
    }
    if (l < CELLS - 64) {              // cells 64..80
        const int cell = l + 64;
        float cnt = bias;
        #pragma unroll
        for (int n = 0; n < KK; ++n) cnt += bs[n * CELLS + cell] * wreg[n];
        float nic = fmaxf(cnt - 1.f, 0.f);
        float m0  = fminf(fmaxf(1.f - nic, 0.f), 1.f) * (-(float)KK);
        float v1 = m0 - nic;
        if (v1 > v0) { v0 = v1; i0 = cell; }
    }
    // 5-step butterfly within the 32-lane group (xor offsets < 32 stay inside)
    #pragma unroll
    for (int off = 16; off > 0; off >>= 1) {
        float ov = __shfl_xor(v0, off, 64);
        int   oi = __shfl_xor(i0, off, 64);
        if (ov > v0 || (ov == v0 && oi < i0)) { v0 = ov; i0 = oi; }
    }
    // all 32 lanes now hold the winning cell; redundant number-argmax
    const int cellstar = i0;
    float m = bs[cellstar]; int nstar = 0;
    #pragma unroll
    for (int n = 1; n < KK; ++n) {
        float v = bs[n * CELLS + cellstar];
        if (v > m) { m = v; nstar = n; }
    }
    if (l == 0) {
        const float ri  = rindex[board];
        const float cms = fminf(fmaxf(m * wreg[nstar] + bias, 0.f), 1.f);
        const int   es  = nstar * CELLS + cellstar;      // < 729
        v4f mt;
        ((int*)&mt)[0] = es | (cellstar << 16);
        mt.y = m; mt.z = cms; mt.w = ri;
        meta[board]   = mt;
        out_ri[board] = ri + 1.f;
    }
}

// ---------------- Kernel 2: pure streaming map ----------------
// No LDS, no shuffles, no barriers. Each thread: 4 v4f of sudoku + rmask
// (per-instruction perfectly coalesced: consecutive lanes -> consecutive
// 16B), one 16B meta load per v4f (L1 broadcast), nontemporal stores.
__global__ __launch_bounds__(256) void apply_kernel(
    const float* __restrict__ sudoku,
    const float* __restrict__ rmask,
    const float* __restrict__ conv_b,
    const v4f* __restrict__ meta,
    float* __restrict__ out,
    int Btot)
{
    const float bias = conv_b[0];
    const float cmp  = fminf(fmaxf(bias, 0.f), 1.f);

    const int tid = threadIdx.x;
    const size_t tbase = (size_t)blockIdx.x * AP_V4;
    const v4f* gs = (const v4f*)sudoku;
    const v4f* gr = (const v4f*)rmask;
    v4f* os = (v4f*)out;
    v4f* orr = (v4f*)(out + (size_t)Btot * BOARD);

    #pragma unroll
    for (int k = 0; k < 4; ++k) {
        const unsigned gv = (unsigned)tbase + k * 256 + tid;  // v4f index
        v4f s = gs[gv];
        v4f r = gr[gv];

        const unsigned f0 = gv * 4u;            // flat element index of s.x
        unsigned b  = f0 / 729u;                // board (magic div)
        int e0 = (int)(f0 - b * 729u);          // 0..725 (or up to 728)
        v4f mt = meta[b];
        int   p1   = ((const int*)&mt)[0];
        int   es1  = p1 & 0xFFFF;
        int   cs1  = p1 >> 16;
        float m1   = mt.y, cms1 = mt.z, ri1 = mt.w;

        // straddle: elements e0..e0+3 cross the board boundary iff e0 >= 726
        int   es2 = es1, cs2 = cs1;
        float m2 = m1, cms2 = cms1, ri2 = ri1;
        if (e0 >= BOARD - 3) {
            unsigned b1 = b + 1; if (b1 >= (unsigned)Btot) b1 = b;
            v4f mt2 = meta[b1];
            int p2 = ((const int*)&mt2)[0];
            es2 = p2 & 0xFFFF; cs2 = p2 >> 16;
            m2 = mt2.y; cms2 = mt2.z; ri2 = mt2.w;
        }

        const int cell0 = e0 % 81;
        float so[4], ro[4];
        #pragma unroll
        for (int j = 0; j < 4; ++j) {
            int e = e0 + j;
            int cell = cell0 + j; if (cell >= CELLS) cell -= CELLS;
            int   es = es1, cs = cs1;
            float mm = m1, cms = cms1, ri = ri1;
            if (e >= BOARD) {                   // next board (e-729 in 0..2)
                e -= BOARD; cell = e;
                es = es2; cs = cs2; mm = m2; cms = cms2; ri = ri2;
            }
            float sj = s[j];
            float rj = r[j];
            float ov  = (e == es) ? mm : 0.f;
            float cm  = (cell == cs) ? cms : cmp;
            float orm = sj * cm * (1.f - ov);
            float rmo = fmaxf(rj, ri * orm);
            rmo = fmaxf(rmo, (ri - 1.f) * ov);
            so[j] = sj * (1.f - orm);
            ro[j] = rmo;
        }
        v4f sv; sv.x = so[0]; sv.y = so[1]; sv.z = so[2]; sv.w = so[3];
        v4f rv; rv.x = ro[0]; rv.y = ro[1]; rv.z = ro[2]; rv.w = ro[3];
        __builtin_nontemporal_store(sv, &os[gv]);
        __builtin_nontemporal_store(rv, &orr[gv]);
    }
}

extern "C" void kernel_launch(void* const* d_in, const int* in_sizes, int n_in,
                              void* d_out, int out_size, void* d_ws, size_t ws_size,
                              hipStream_t stream) {
    const float* sudoku = (const float*)d_in[0];
    const float* rmask  = (const float*)d_in[1];
    const float* rindex = (const float*)d_in[2];
    const float* conv_w = (const float*)d_in[3];
    const float* conv_b = (const float*)d_in[4];
    float* out = (float*)d_out;

    const int Btot = in_sizes[2];                      // 32768 boards
    v4f* meta = (v4f*)d_ws;                            // 16 B per board

    const int nb1 = Btot / B1;                         // 4096
    select_kernel<<<nb1, 256, 0, stream>>>(
        sudoku, rindex, conv_w, conv_b, meta,
        out + (size_t)Btot * BOARD * 2, Btot);

    const int nb2 = (Btot * BOARD / 4) / AP_V4;        // 5832
    apply_kernel<<<nb2, 256, 0, stream>>>(
        sudoku, rmask, conv_b, meta, out, Btot);
}